// Round 3
// baseline (11949.814 us; speedup 1.0000x reference)
//
#include <hip/hip_runtime.h>
#include <math.h>

#define B_  64
#define S_  512
#define I_  512
#define H_  512
#define G4  2048   // 4*H
#define NBLK 256
static const size_t BSH = (size_t)B_ * S_ * H_;

// ---------------- workspace layout ----------------
// pre path:  [0] hg[2][512][64] (256KB) | [256KB] ctr[512*4*16] (128KB) | [16MB] xw (256MB)
// fallback:  [1MB] Ut 4MB | [5MB] Wt 4MB | [9MB] bcat | h0/h1/c
static const size_t OFF_HG  = 0;
static const size_t OFF_CTR = 256 * 1024;
static const size_t OFF_UT  = 1ull << 20;
static const size_t OFF_WT  = OFF_UT + (size_t)G4 * 512 * 4;
static const size_t OFF_B   = OFF_WT + (size_t)G4 * 512 * 4;
static const size_t OFF_H0  = OFF_B + 64 * 1024;
static const size_t OFF_H1  = OFF_H0 + (size_t)B_ * H_ * 4;
static const size_t OFF_C   = OFF_H1 + (size_t)B_ * H_ * 4;
static const size_t OFF_XW  = 16ull * 1024 * 1024;
static const size_t PRE_BYTES = OFF_XW + (size_t)S_ * B_ * G4 * 4;  // ~272 MB

// ======================= common / fallback kernels =======================

__global__ __launch_bounds__(256) void transpose512(const float* __restrict__ src,
                                                    float* __restrict__ dst) {
    __shared__ float t[32][33];
    int k0 = blockIdx.x * 32, c0 = blockIdx.y * 32;
    int tx = threadIdx.x & 31, ty = threadIdx.x >> 5;
    #pragma unroll
    for (int i = 0; i < 32; i += 8)
        t[ty + i][tx] = src[(size_t)(k0 + ty + i) * 512 + c0 + tx];
    __syncthreads();
    #pragma unroll
    for (int i = 0; i < 32; i += 8)
        dst[(size_t)(c0 + ty + i) * 512 + k0 + tx] = t[tx][ty + i];
}

__global__ __launch_bounds__(256) void pack_bias(const float* __restrict__ bf,
                                                 const float* __restrict__ bi,
                                                 const float* __restrict__ bo,
                                                 const float* __restrict__ bc,
                                                 float* __restrict__ bcat) {
    int i = blockIdx.x * 256 + threadIdx.x;
    const float* p = (i < 512) ? bf : (i < 1024) ? bi : (i < 1536) ? bo : bc;
    bcat[i] = p[i & 511];
}

__global__ __launch_bounds__(256) void zero_hc(float* __restrict__ h0, float* __restrict__ c) {
    int i = blockIdx.x * 256 + threadIdx.x;
    h0[i] = 0.f;
    c[i] = 0.f;
}

__global__ __launch_bounds__(256) void zero_pre(float* __restrict__ hg, unsigned* __restrict__ ctr) {
    int i = blockIdx.x * 256 + threadIdx.x;   // grid 256 -> 65536
    hg[i] = 0.f;
    if (i < 512 * 4 * 16) ctr[i] = 0u;
}

// xw[(s*64+b)*2048 + col] = x[row=b*512+s][:] . Wg[:][col] + bcat[col]
__global__ __launch_bounds__(256) void proj_gemm(
    const float* __restrict__ x,
    const float* __restrict__ Wf, const float* __restrict__ Wi,
    const float* __restrict__ Wo, const float* __restrict__ Wc,
    const float* __restrict__ bcat, float* __restrict__ xw) {
    __shared__ float As[16][136];
    __shared__ float Bs[16][64];
    int m0 = blockIdx.x * 128, n0 = blockIdx.y * 64;
    int gate = n0 >> 9;
    const float* Wg = (gate == 0) ? Wf : (gate == 1) ? Wi : (gate == 2) ? Wo : Wc;
    int cg0 = n0 & 511;
    int tid = threadIdx.x;
    int tm = tid >> 4, tn = tid & 15;
    float acc[8][4] = {};
    for (int kt = 0; kt < 512; kt += 16) {
        {
            int r = tid >> 2, kq = (tid & 3) * 4;
            #pragma unroll
            for (int p = 0; p < 2; ++p) {
                int row = m0 + r + p * 64;
                float4 v = *(const float4*)&x[(size_t)row * I_ + kt + kq];
                As[kq + 0][r + p * 64] = v.x;
                As[kq + 1][r + p * 64] = v.y;
                As[kq + 2][r + p * 64] = v.z;
                As[kq + 3][r + p * 64] = v.w;
            }
            int kr = tid >> 4, cl = (tid & 15) * 4;
            *(float4*)&Bs[kr][cl] = *(const float4*)&Wg[(size_t)(kt + kr) * 512 + cg0 + cl];
        }
        __syncthreads();
        #pragma unroll
        for (int k = 0; k < 16; ++k) {
            float a[8], b[4];
            *(float4*)&a[0] = *(float4*)&As[k][tm * 8];
            *(float4*)&a[4] = *(float4*)&As[k][tm * 8 + 4];
            *(float4*)&b[0] = *(float4*)&Bs[k][tn * 4];
            #pragma unroll
            for (int i2 = 0; i2 < 8; ++i2)
                #pragma unroll
                for (int j = 0; j < 4; ++j) acc[i2][j] += a[i2] * b[j];
        }
        __syncthreads();
    }
    #pragma unroll
    for (int i2 = 0; i2 < 8; ++i2) {
        int row = m0 + tm * 8 + i2;
        int b = row >> 9, s = row & 511;
        int col = n0 + tn * 4;
        float4 v;
        v.x = acc[i2][0] + bcat[col + 0];
        v.y = acc[i2][1] + bcat[col + 1];
        v.z = acc[i2][2] + bcat[col + 2];
        v.w = acc[i2][3] + bcat[col + 3];
        *(float4*)&xw[((size_t)s * 64 + b) * G4 + col] = v;
    }
}

// ======================= persistent scan (pre path) =======================
//
// Grid: 256 blocks x 256 thr, 1/CU.  Block (cb=bid&63, bb=bid>>6):
//   owns 8 hidden cols (x4 gates = 32 g4-cols) x 16 batch rows.
// U fragment per thread lives in VGPRs for the whole scan (128 VGPR).
// h exchanged via global hg[2][hidden][batch].
// Sync: per-step barrier among ONLY the 64 blocks sharing bb (the exclusive
// producers of this block's 16 batch rows of h). 4 independent groups.
// c state lives in registers of the 128 gate-threads.

__device__ __forceinline__ void groupbar(unsigned* ctr, int idx, unsigned n) {
    __threadfence();                       // release: make h writes visible device-wide
    __syncthreads();
    if (threadIdx.x == 0) {
        __hip_atomic_fetch_add(&ctr[idx], 1u, __ATOMIC_ACQ_REL, __HIP_MEMORY_SCOPE_AGENT);
        while (__hip_atomic_load(&ctr[idx], __ATOMIC_ACQUIRE, __HIP_MEMORY_SCOPE_AGENT) < n)
            __builtin_amdgcn_s_sleep(1);
    }
    __syncthreads();
    __threadfence();                       // acquire: no stale h reads
}

__global__ __launch_bounds__(256, 1) void lstm_scan(
    const float* __restrict__ U0, const float* __restrict__ U1,
    const float* __restrict__ U2, const float* __restrict__ U3,
    const float* __restrict__ xw,     // [S][B][G4] (bias already added)
    float* __restrict__ hg,           // [2][512][64]  (hidden-major)
    unsigned* __restrict__ ctr,       // [(s*4+bb)*16]
    float* __restrict__ out) {
    __shared__ float hs[512][20];     // h, k-major, padded (bank-clean: 2-way max)
    __shared__ float gs[16][33];      // reduced gate pre-activations

    const int bid = blockIdx.x;
    const int cb = bid & 63, bb = bid >> 6;
    const int hc0 = cb * 8, b0 = bb * 16;
    const int tid = threadIdx.x;
    const int kp = tid & 15;          // k-partition (16-way split of K)
    const int g  = tid >> 4;          // 16 output groups
    const int rg = g >> 3, cg = g & 7;
    const int r0 = rg * 8;            // 8 rows per thread
    const int c0 = cg * 4;            // 4 local g4-cols per thread
    const int gate = c0 >> 3;         // local col c = gate*8 + hcl
    const int hcl0 = c0 & 7;          // 0 or 4
    const float* Ug = (gate == 0) ? U0 : (gate == 1) ? U1 : (gate == 2) ? U2 : U3;

    // --- load U fragment into registers: u[j] = U[k=16j+kp][hc0+hcl0 .. +3] ---
    float4 u[32];
    #pragma unroll
    for (int j = 0; j < 32; ++j)
        u[j] = *(const float4*)&Ug[(size_t)(16 * j + kp) * 512 + hc0 + hcl0];

    // gate-thread identity (tid < 128): row er, hidden col ehc
    const int er = tid & 15, ehc = tid >> 4;
    float creg = 0.f;

    // staging identity
    const int sw = tid >> 6, skk = (tid >> 2) & 15, sm = tid & 3;

    for (int s = 0; s < S_; ++s) {
        const float* hcur = hg + (size_t)(s & 1) * 32768;
        float* hnxt = hg + (size_t)((s & 1) ^ 1) * 32768;

        // prefetch this step's xw values (consumed in epilogue)
        float xf = 0.f, xi = 0.f, xo = 0.f, xc = 0.f;
        if (tid < 128) {
            const float* xp = xw + ((size_t)s * 64 + b0 + er) * G4 + hc0 + ehc;
            xf = xp[0]; xi = xp[512]; xo = xp[1024]; xc = xp[1536];
        }

        // stage h (k-major): hs[k][r] = h[b0+r][k]; hg is [hidden][batch] so this
        // is a straight float4 copy (no transpose). Bank-even writes.
        #pragma unroll
        for (int t = 0; t < 8; ++t) {
            int k = t * 64 + sw * 16 + skk;
            float4 v = *(const float4*)&hcur[k * 64 + b0 + sm * 4];
            *(float4*)&hs[k][sm * 4] = v;
        }
        __syncthreads();

        // --- k-loop: acc[i][jj] += h[r0+i][k] * U[k][c0+jj], k = 16j+kp ---
        float acc[8][4] = {};
        #pragma unroll
        for (int j = 0; j < 32; ++j) {
            int k = 16 * j + kp;
            float4 ha = *(const float4*)&hs[k][r0];
            float4 hb = *(const float4*)&hs[k][r0 + 4];
            float4 uv = u[j];
            float hv[8] = {ha.x, ha.y, ha.z, ha.w, hb.x, hb.y, hb.z, hb.w};
            #pragma unroll
            for (int i = 0; i < 8; ++i) {
                acc[i][0] += hv[i] * uv.x;
                acc[i][1] += hv[i] * uv.y;
                acc[i][2] += hv[i] * uv.z;
                acc[i][3] += hv[i] * uv.w;
            }
        }

        // --- reduce over the 16 k-partitions (butterfly within contiguous 16 lanes) ---
        #pragma unroll
        for (int m = 1; m <= 8; m <<= 1) {
            #pragma unroll
            for (int i = 0; i < 8; ++i)
                #pragma unroll
                for (int jj = 0; jj < 4; ++jj)
                    acc[i][jj] += __shfl_xor(acc[i][jj], m, 64);
        }
        if (kp == 0) {
            #pragma unroll
            for (int i = 0; i < 8; ++i)
                #pragma unroll
                for (int jj = 0; jj < 4; ++jj)
                    gs[r0 + i][c0 + jj] = acc[i][jj];
        }
        __syncthreads();

        // --- gate epilogue: 128 threads, one (row, hidden-col) each ---
        if (tid < 128) {
            float gf = gs[er][ehc]      + xf;
            float gi = gs[er][8 + ehc]  + xi;
            float go = gs[er][16 + ehc] + xo;
            float gc = gs[er][24 + ehc] + xc;
            float f_ = 1.f / (1.f + expf(-gf));
            float i_ = 1.f / (1.f + expf(-gi));
            float o_ = 1.f / (1.f + expf(-go));
            float ch = tanhf(gc);
            creg = f_ * creg + i_ * ch;
            float hn = o_ * tanhf(creg);
            hnxt[(hc0 + ehc) * 64 + b0 + er] = hn;                       // coalesced (er fast)
            out[((size_t)(b0 + er) * S_ + s) * H_ + hc0 + ehc] = hn;
            if (s == S_ - 1) {
                out[BSH + (size_t)(b0 + er) * H_ + hc0 + ehc] = hn;      // h_T
                out[BSH + (size_t)B_ * H_ + (size_t)(b0 + er) * H_ + hc0 + ehc] = creg;  // c_T
            }
        }

        // sync only the 64 blocks (same bb) that produce this block's h rows
        if (s < S_ - 1) groupbar(ctr, (s * 4 + bb) * 16, 64u);
    }
}

// ======================= fallback per-step kernel (small ws) =======================

__global__ __launch_bounds__(256) void lstm_step_fused(
    const float* __restrict__ x, const float* __restrict__ Ut,
    const float* __restrict__ Wt, const float* __restrict__ bcat,
    const float* __restrict__ h_in, float* __restrict__ h_out,
    float* __restrict__ c_st, float* __restrict__ out, int s) {
    __shared__ float hsl[16][512];
    __shared__ float Us[32][68];
    __shared__ float gsl[16][32];
    int cb = blockIdx.x, bb = blockIdx.y;
    int hc0 = cb * 8, b0 = bb * 16;
    int tid = threadIdx.x;
    int col_l = tid & 31;
    int gg = col_l >> 3, cc = col_l & 7;
    int col4 = gg * 512 + hc0 + cc;
    int r0 = tid >> 5;
    {
        const float4* src = (const float4*)&h_in[(size_t)b0 * 512];
        float4* dst = (float4*)&hsl[0][0];
        #pragma unroll
        for (int i = 0; i < 8; ++i) dst[tid + i * 256] = src[tid + i * 256];
    }
    float acc0 = bcat[col4], acc1 = acc0;
    __syncthreads();
    for (int pass = 0; pass < 2; ++pass) {
        const float* Mt = pass ? Wt : Ut;
        if (pass) {
            __syncthreads();
            for (int i = tid; i < 16 * 128; i += 256) {
                int r = i >> 7, kq = i & 127;
                ((float4*)&hsl[r][0])[kq] =
                    ((const float4*)&x[((size_t)(b0 + r) * 512 + s) * 512])[kq];
            }
            __syncthreads();
        }
        for (int kt = 0; kt < 512; kt += 64) {
            int col_s = tid >> 3, kh = tid & 7;
            const float* mp = Mt + (size_t)((col_s >> 3) * 512 + hc0 + (col_s & 7)) * 512 + kt + kh * 8;
            *(float4*)&Us[col_s][kh * 8]     = *(const float4*)&mp[0];
            *(float4*)&Us[col_s][kh * 8 + 4] = *(const float4*)&mp[4];
            __syncthreads();
            #pragma unroll
            for (int kk = 0; kk < 64; kk += 4) {
                float4 uv = *(float4*)&Us[col_l][kk];
                float4 ha = *(float4*)&hsl[r0][kt + kk];
                float4 hb = *(float4*)&hsl[r0 + 8][kt + kk];
                acc0 += uv.x * ha.x + uv.y * ha.y + uv.z * ha.z + uv.w * ha.w;
                acc1 += uv.x * hb.x + uv.y * hb.y + uv.z * hb.z + uv.w * hb.w;
            }
            __syncthreads();
        }
    }
    gsl[r0][col_l] = acc0;
    gsl[r0 + 8][col_l] = acc1;
    __syncthreads();
    if (tid < 128) {
        int r = tid >> 3, cc2 = tid & 7;
        float gf = gsl[r][cc2], gi = gsl[r][8 + cc2], go = gsl[r][16 + cc2], gc = gsl[r][24 + cc2];
        float f_ = 1.f / (1.f + expf(-gf));
        float i_ = 1.f / (1.f + expf(-gi));
        float o_ = 1.f / (1.f + expf(-go));
        float ch = tanhf(gc);
        int b = b0 + r, hc = hc0 + cc2;
        size_t idx = (size_t)b * 512 + hc;
        float cn = f_ * c_st[idx] + i_ * ch;
        float hn = o_ * tanhf(cn);
        c_st[idx] = cn;
        h_out[idx] = hn;
        out[((size_t)b * S_ + s) * H_ + hc] = hn;
    }
}

__global__ __launch_bounds__(256) void copy_hc(const float* __restrict__ hT,
                                               const float* __restrict__ cT,
                                               float* __restrict__ out) {
    int i = blockIdx.x * 256 + threadIdx.x;
    out[BSH + i] = hT[i];
    out[BSH + B_ * H_ + i] = cT[i];
}

// ======================= launch =======================

extern "C" void kernel_launch(void* const* d_in, const int* in_sizes, int n_in,
                              void* d_out, int out_size, void* d_ws, size_t ws_size,
                              hipStream_t stream) {
    const float* x  = (const float*)d_in[0];
    const float* Wf = (const float*)d_in[1];
    const float* Uf = (const float*)d_in[2];
    const float* bf = (const float*)d_in[3];
    const float* Wi = (const float*)d_in[4];
    const float* Ui = (const float*)d_in[5];
    const float* bi = (const float*)d_in[6];
    const float* Wo = (const float*)d_in[7];
    const float* Uo = (const float*)d_in[8];
    const float* bo = (const float*)d_in[9];
    const float* Wc = (const float*)d_in[10];
    const float* Uc = (const float*)d_in[11];
    const float* bc = (const float*)d_in[12];
    float* out = (float*)d_out;
    char* ws = (char*)d_ws;
    float* hg      = (float*)(ws + OFF_HG);
    unsigned* ctr  = (unsigned*)(ws + OFF_CTR);
    float* xw      = (float*)(ws + OFF_XW);
    float* bcat    = (float*)(ws + OFF_B);
    const bool pre = (ws_size >= PRE_BYTES);

    dim3 tb(256);
    if (pre) {
        pack_bias<<<8, tb, 0, stream>>>(bf, bi, bo, bc, bcat);
        zero_pre<<<256, tb, 0, stream>>>(hg, ctr);
        proj_gemm<<<dim3(256, 32), tb, 0, stream>>>(x, Wf, Wi, Wo, Wc, bcat, xw);
        lstm_scan<<<NBLK, tb, 0, stream>>>(Uf, Ui, Uo, Uc, xw, hg, ctr, out);
    } else {
        float* Ut = (float*)(ws + OFF_UT);
        float* Wt = (float*)(ws + OFF_WT);
        float* h0 = (float*)(ws + OFF_H0);
        float* h1 = (float*)(ws + OFF_H1);
        float* cb = (float*)(ws + OFF_C);
        dim3 tg(16, 16);
        transpose512<<<tg, tb, 0, stream>>>(Uf, Ut + 0 * 512 * 512);
        transpose512<<<tg, tb, 0, stream>>>(Ui, Ut + 1 * 512 * 512);
        transpose512<<<tg, tb, 0, stream>>>(Uo, Ut + 2 * 512 * 512);
        transpose512<<<tg, tb, 0, stream>>>(Uc, Ut + 3 * 512 * 512);
        transpose512<<<tg, tb, 0, stream>>>(Wf, Wt + 0 * 512 * 512);
        transpose512<<<tg, tb, 0, stream>>>(Wi, Wt + 1 * 512 * 512);
        transpose512<<<tg, tb, 0, stream>>>(Wo, Wt + 2 * 512 * 512);
        transpose512<<<tg, tb, 0, stream>>>(Wc, Wt + 3 * 512 * 512);
        pack_bias<<<8, tb, 0, stream>>>(bf, bi, bo, bc, bcat);
        zero_hc<<<128, tb, 0, stream>>>(h0, cb);
        for (int s = 0; s < S_; ++s) {
            float* hin  = (s & 1) ? h1 : h0;
            float* hout = (s & 1) ? h0 : h1;
            lstm_step_fused<<<dim3(64, 4), tb, 0, stream>>>(x, Ut, Wt, bcat, hin, hout, cb, out, s);
        }
        copy_hc<<<128, tb, 0, stream>>>(h0, cb, out);
    }
}